// Round 1
// baseline (105.761 us; speedup 1.0000x reference)
//
#include <hip/hip_runtime.h>
#include <math.h>

// Chamfer loss, B=16, N=M=4096, D=3, fp32.
// result = sum over all 2*B*N nearest-neighbor sqrt-distances / (2*B*N)
//
// Structure:
//  kernel 1 (chamfer_main): 512 blocks. Each block = (dir, batch, n-chunk, m-split).
//    Stages its m-segment (512 pts) into LDS pre-scaled as (-2x,-2y,-2z,|t|^2),
//    each thread holds KPT=8 n-points in regs, inner loop does 4 m-points per
//    iter via 4x ds_read_b128 (wave-uniform broadcast), 3 fma + 1 min per pair.
//    Writes partial min of (|t|^2 - 2 p.t) per (dir,b,n,split) to ws.
//  kernel 2 (chamfer_combine): min over 8 splits, + |p|^2, clamp, sqrt,
//    block-reduce, per-block sums to ws.
//  kernel 3 (chamfer_final): reduce 512 block sums, scale, write d_out.

#define BATCH   16
#define NPTS    4096
#define THREADS 256
#define KPT     8
#define NCHUNKS 2          // NPTS / (THREADS*KPT)
#define SPLITS  8
#define MSEG    (NPTS / SPLITS)   // 512
#define NITEMS  (2 * BATCH * NPTS)       // 131072
#define CBLOCKS (NITEMS / THREADS)       // 512

__global__ __launch_bounds__(THREADS) void chamfer_main(
    const float* __restrict__ pred, const float* __restrict__ target,
    float* __restrict__ partial)
{
    __shared__ __align__(16) float xs[MSEG];
    __shared__ __align__(16) float ys[MSEG];
    __shared__ __align__(16) float zs[MSEG];
    __shared__ __align__(16) float ts[MSEG];

    int id = blockIdx.x;
    int split = id & (SPLITS - 1);  id >>= 3;
    int chunk = id & (NCHUNKS - 1); id >>= 1;
    int b     = id & (BATCH - 1);   id >>= 4;
    int dir   = id;                 // 0: pred->target, 1: target->pred

    const float* src = dir ? target : pred;   // n-side (query points)
    const float* dst = dir ? pred : target;   // m-side (candidate points)

    const float* dbase = dst + (size_t)b * (NPTS * 3) + (size_t)split * (MSEG * 3);
    int tid = threadIdx.x;

    // Stage m-segment, pre-scaled.
    for (int i = tid; i < MSEG; i += THREADS) {
        float x = dbase[i * 3 + 0];
        float y = dbase[i * 3 + 1];
        float z = dbase[i * 3 + 2];
        xs[i] = -2.0f * x;
        ys[i] = -2.0f * y;
        zs[i] = -2.0f * z;
        ts[i] = x * x + y * y + z * z;
    }
    __syncthreads();

    // Load KPT query points into registers.
    const float* sbase = src + (size_t)b * (NPTS * 3) + (size_t)chunk * (THREADS * KPT * 3);
    float px[KPT], py[KPT], pz[KPT], mn[KPT];
#pragma unroll
    for (int k = 0; k < KPT; ++k) {
        int n = k * THREADS + tid;
        px[k] = sbase[n * 3 + 0];
        py[k] = sbase[n * 3 + 1];
        pz[k] = sbase[n * 3 + 2];
        mn[k] = 1e30f;
    }

    const float4* x4 = (const float4*)xs;
    const float4* y4 = (const float4*)ys;
    const float4* z4 = (const float4*)zs;
    const float4* t4 = (const float4*)ts;

#pragma unroll 2
    for (int mm = 0; mm < MSEG / 4; ++mm) {
        float4 xv = x4[mm];
        float4 yv = y4[mm];
        float4 zv = z4[mm];
        float4 tv = t4[mm];
#pragma unroll
        for (int k = 0; k < KPT; ++k) {
            float d0 = fmaf(px[k], xv.x, fmaf(py[k], yv.x, fmaf(pz[k], zv.x, tv.x)));
            float d1 = fmaf(px[k], xv.y, fmaf(py[k], yv.y, fmaf(pz[k], zv.y, tv.y)));
            float d2 = fmaf(px[k], xv.z, fmaf(py[k], yv.z, fmaf(pz[k], zv.z, tv.z)));
            float d3 = fmaf(px[k], xv.w, fmaf(py[k], yv.w, fmaf(pz[k], zv.w, tv.w)));
            float m01 = fminf(d0, d1);
            float m23 = fminf(d2, d3);
            mn[k] = fminf(mn[k], fminf(m01, m23));
        }
    }

    // Partial layout: partial[((dir*BATCH + b)*NPTS + n)*SPLITS + split]
    size_t gbase = ((size_t)dir * BATCH + b) * NPTS;
#pragma unroll
    for (int k = 0; k < KPT; ++k) {
        int n = chunk * (THREADS * KPT) + k * THREADS + tid;
        partial[(gbase + n) * SPLITS + split] = mn[k];
    }
}

__device__ inline float block_reduce_sum(float v, float* red) {
#pragma unroll
    for (int off = 32; off > 0; off >>= 1)
        v += __shfl_down(v, off);
    int lane = threadIdx.x & 63;
    int wave = threadIdx.x >> 6;
    if (lane == 0) red[wave] = v;
    __syncthreads();
    float s = 0.0f;
    if (threadIdx.x == 0) {
        s = red[0] + red[1] + red[2] + red[3];
    }
    return s;
}

__global__ __launch_bounds__(THREADS) void chamfer_combine(
    const float* __restrict__ pred, const float* __restrict__ target,
    const float* __restrict__ partial, float* __restrict__ blocksum)
{
    __shared__ float red[4];
    int g = blockIdx.x * THREADS + threadIdx.x;   // 0..131071
    int dir = g >> 16;                            // 0..1
    int bn  = g & 65535;                          // b*NPTS + n

    const float* src = dir ? target : pred;
    float x = src[bn * 3 + 0];
    float y = src[bn * 3 + 1];
    float z = src[bn * 3 + 2];
    float pp = x * x + y * y + z * z;

    const float4* p4 = (const float4*)(partial + (size_t)g * SPLITS);
    float4 a = p4[0];
    float4 c = p4[1];
    float m = fminf(fminf(fminf(a.x, a.y), fminf(a.z, a.w)),
                    fminf(fminf(c.x, c.y), fminf(c.z, c.w)));
    float d2 = m + pp;
    float d = sqrtf(fmaxf(d2, 0.0f));

    float s = block_reduce_sum(d, red);
    if (threadIdx.x == 0) blocksum[blockIdx.x] = s;
}

__global__ __launch_bounds__(THREADS) void chamfer_final(
    const float* __restrict__ blocksum, float* __restrict__ out)
{
    __shared__ float red[4];
    float v = blocksum[threadIdx.x] + blocksum[threadIdx.x + THREADS];
    float s = block_reduce_sum(v, red);
    if (threadIdx.x == 0) out[0] = s * (1.0f / (float)NITEMS);
}

extern "C" void kernel_launch(void* const* d_in, const int* in_sizes, int n_in,
                              void* d_out, int out_size, void* d_ws, size_t ws_size,
                              hipStream_t stream) {
    const float* pred   = (const float*)d_in[0];
    const float* target = (const float*)d_in[1];
    float* out = (float*)d_out;

    float* partial  = (float*)d_ws;                       // NITEMS * SPLITS floats = 4 MB
    float* blocksum = partial + (size_t)NITEMS * SPLITS;  // CBLOCKS floats

    chamfer_main<<<2 * BATCH * NCHUNKS * SPLITS, THREADS, 0, stream>>>(pred, target, partial);
    chamfer_combine<<<CBLOCKS, THREADS, 0, stream>>>(pred, target, partial, blocksum);
    chamfer_final<<<1, THREADS, 0, stream>>>(blocksum, out);
}